// Round 10
// baseline (206.728 us; speedup 1.0000x reference)
//
#include <hip/hip_runtime.h>
#include <math.h>

// Problem constants (match reference)
constexpr int   B_    = 2048;
constexpr int   L_    = 8192;
constexpr int   G_    = 256;
constexpr float BETA_ = 0.01f;

constexpr int KS     = 16;           // k-splits
constexpr int KPER   = L_ / KS;      // 512
constexpr int KSTEPS = KPER / 32;    // 16 MFMA k-steps per block

typedef short bf16x8 __attribute__((ext_vector_type(8)));   // 8 bf16 (4 VGPR)
typedef float f32x4  __attribute__((ext_vector_type(4)));   // MFMA C/D

// log(sigmoid(-x)) = -softplus(x); HW transcendentals (absmax 0.0, R2-R9).
__device__ __forceinline__ float log_sigmoid_neg(float x) {
    return -(fmaxf(x, 0.0f) + __logf(1.0f + __expf(-fabsf(x))));
}

// fp32 -> bf16 round-to-nearest-even (3 VALU, finite inputs only)
__device__ __forceinline__ short bf16_rn(float f) {
    unsigned u = __float_as_uint(f);
    u += 0x7FFFu + ((u >> 16) & 1u);
    return (short)(u >> 16);
}

// ---------------------------------------------------------------------------
// k0: group_ids int32 -> u8 (G=256 fits exactly). 8192 elems, trivial.
// ---------------------------------------------------------------------------
extern "C" __global__ __launch_bounds__(1024)
void gid8_kernel(const int* __restrict__ group_ids, unsigned char* __restrict__ g8)
{
    const int i = blockIdx.x * 1024 + threadIdx.x;
    g8[i] = (unsigned char)group_ids[i];
}

// ---------------------------------------------------------------------------
// Main: the segment-sum as MFMA GEMM with on-the-fly one-hot B.
//   C1[b,g] = sum_l lognot(logits[b,l]) * [gid(l)==g]   (bf16 MFMA, fp32 acc)
//   C2[b,g] = sum_l y[b,l]              * [gid(l)==g]   (exact small ints)
// No LDS, no barriers, no scatter: K-loop = coalesced A stream + in-register
// B one-hot build + 16 MFMA. R4-R9's block-phased structure capped vmem duty
// at ~45-50% (45us floor); this loop is copy-shaped so waves stream freely.
// Wave: 16 rows x 128 cols (8 col-frags x2 mats = 64 acc VGPRs).
// Block: 4 waves = 64 rows x 128 cols. Grid: 32 rowtiles x 2 colhalves x KS.
// K-split partials -> global fp32 atomicAdd (C zeroed via memsetAsync).
// ---------------------------------------------------------------------------
extern "C" __global__ __launch_bounds__(256, 3)
void gemm_kernel(const float* __restrict__ logits,
                 const int*   __restrict__ true_y,
                 const unsigned char* __restrict__ g8,
                 float* __restrict__ C1,
                 float* __restrict__ C2)
{
    const int t    = threadIdx.x;
    const int w    = t >> 6;          // wave id 0..3 -> row-group
    const int lane = t & 63;
    const int m    = lane & 15;       // A row within 16-tile == B col within 16-tile
    const int q    = lane >> 4;       // k-quad: lane holds k = q*8 + j

    const int bid = blockIdx.x;       // 32 x 2 x 16 = 1024
    const int rt  = bid & 31;         // row tile (64 rows)
    const int ch  = (bid >> 5) & 1;   // col half (128 cols)
    const int ks  = bid >> 6;         // k-split 0..15

    const int    row   = rt * 64 + w * 16 + m;
    const size_t roff  = (size_t)row * L_;
    const float* xp    = logits + roff;
    const int*   yp    = true_y + roff;
    const int    mycol = ch * 128 + m;           // + c*16 per frag

    f32x4 acc1[8], acc2[8];
    #pragma unroll
    for (int c = 0; c < 8; ++c) {
        acc1[c] = (f32x4){0.f, 0.f, 0.f, 0.f};
        acc2[c] = (f32x4){0.f, 0.f, 0.f, 0.f};
    }

    for (int kk = 0; kk < KSTEPS; ++kk) {
        const int kb = ks * KPER + kk * 32 + q * 8;   // this lane's 8 k's

        const float4 x0 = *(const float4*)(xp + kb);
        const float4 x1 = *(const float4*)(xp + kb + 4);
        const int4   y0 = *(const int4*)(yp + kb);
        const int4   y1 = *(const int4*)(yp + kb + 4);
        const uint2  gv = *(const uint2*)(g8 + kb);   // 8 group bytes (L2-hot)

        // A1 = lognot(x) in bf16; A2 = y in bf16 (exact 0/1)
        bf16x8 a1, a2;
        a1[0] = bf16_rn(log_sigmoid_neg(x0.x));
        a1[1] = bf16_rn(log_sigmoid_neg(x0.y));
        a1[2] = bf16_rn(log_sigmoid_neg(x0.z));
        a1[3] = bf16_rn(log_sigmoid_neg(x0.w));
        a1[4] = bf16_rn(log_sigmoid_neg(x1.x));
        a1[5] = bf16_rn(log_sigmoid_neg(x1.y));
        a1[6] = bf16_rn(log_sigmoid_neg(x1.z));
        a1[7] = bf16_rn(log_sigmoid_neg(x1.w));
        a2[0] = y0.x ? (short)0x3F80 : (short)0;
        a2[1] = y0.y ? (short)0x3F80 : (short)0;
        a2[2] = y0.z ? (short)0x3F80 : (short)0;
        a2[3] = y0.w ? (short)0x3F80 : (short)0;
        a2[4] = y1.x ? (short)0x3F80 : (short)0;
        a2[5] = y1.y ? (short)0x3F80 : (short)0;
        a2[6] = y1.z ? (short)0x3F80 : (short)0;
        a2[7] = y1.w ? (short)0x3F80 : (short)0;

        unsigned gb[8];
        gb[0] =  gv.x        & 255u;
        gb[1] = (gv.x >>  8) & 255u;
        gb[2] = (gv.x >> 16) & 255u;
        gb[3] =  gv.x >> 24;
        gb[4] =  gv.y        & 255u;
        gb[5] = (gv.y >>  8) & 255u;
        gb[6] = (gv.y >> 16) & 255u;
        gb[7] =  gv.y >> 24;

        #pragma unroll
        for (int c = 0; c < 8; ++c) {
            const unsigned cc = (unsigned)(mycol + c * 16);
            bf16x8 b;
            #pragma unroll
            for (int j = 0; j < 8; ++j)
                b[j] = (gb[j] == cc) ? (short)0x3F80 : (short)0;
            acc1[c] = __builtin_amdgcn_mfma_f32_16x16x32_bf16(a1, b, acc1[c], 0, 0, 0);
            acc2[c] = __builtin_amdgcn_mfma_f32_16x16x32_bf16(a2, b, acc2[c], 0, 0, 0);
        }
    }

    // epilogue: k-split partials -> global fp32 atomic accumulate
    // C/D layout (m89-verified): col = lane&15, row = (lane>>4)*4 + reg
    #pragma unroll
    for (int c = 0; c < 8; ++c) {
        const int col = ch * 128 + c * 16 + m;
        #pragma unroll
        for (int r = 0; r < 4; ++r) {
            const int orow = rt * 64 + w * 16 + q * 4 + r;
            atomicAdd(&C1[orow * G_ + col], acc1[c][r]);
            atomicAdd(&C2[orow * G_ + col], acc2[c][r]);
        }
    }
}

// ---------------------------------------------------------------------------
// Finish: per-(b,g) BCE term from grp_log + count, global reduce. 4 MB read.
// ---------------------------------------------------------------------------
extern "C" __global__ __launch_bounds__(256)
void reduce_kernel(const float* __restrict__ C1,
                   const float* __restrict__ C2,
                   float* __restrict__ out)
{
    __shared__ float s_part[4];
    const int t = threadIdx.x;
    const int b = blockIdx.x;        // 256 blocks

    float s = 0.0f;
    #pragma unroll
    for (int i = 0; i < 8; ++i) {
        const int idx = (b * 8 + i) * G_ + t;   // row-major [2048][256], coalesced
        const float gl  = C1[idx];
        const float cnt = C2[idx];
        float term;
        if (cnt > 0.5f) {
            term = fmaxf(gl, -100.0f);                    // meta_y = 1: log(p)
        } else {
            // gl==0 (empty/never-true group) -> log1p(-1) = -inf -> clamp
            term = fmaxf(log1pf(-__expf(gl)), -100.0f);   // meta_y = 0
        }
        s += term;
    }

    #pragma unroll
    for (int off = 32; off > 0; off >>= 1)
        s += __shfl_down(s, off, 64);
    if ((t & 63) == 0) s_part[t >> 6] = s;
    __syncthreads();

    if (t == 0) {
        const float tot = s_part[0] + s_part[1] + s_part[2] + s_part[3];
        atomicAdd(out, tot * (-BETA_ / ((float)B_ * (float)G_)));
    }
}

extern "C" void kernel_launch(void* const* d_in, const int* in_sizes, int n_in,
                              void* d_out, int out_size, void* d_ws, size_t ws_size,
                              hipStream_t stream) {
    const float* logits    = (const float*)d_in[0];
    const int*   true_y    = (const int*)d_in[1];
    const int*   group_ids = (const int*)d_in[2];
    float*       out       = (float*)d_out;

    // workspace: [0,8192) g8 u8; then C1 [2048][256] fp32; then C2 same. ~4.2 MB.
    unsigned char* g8 = (unsigned char*)d_ws;
    float* C1 = (float*)((char*)d_ws + 8192);
    float* C2 = C1 + B_ * G_;

    hipMemsetAsync(out, 0, sizeof(float), stream);
    hipMemsetAsync(C1, 0, 2 * B_ * G_ * sizeof(float), stream);   // C1+C2

    gid8_kernel<<<L_ / 1024, 1024, 0, stream>>>(group_ids, g8);
    gemm_kernel<<<32 * 2 * KS, 256, 0, stream>>>(logits, true_y, g8, C1, C2);
    reduce_kernel<<<B_ / 8, 256, 0, stream>>>(C1, C2, out);
}

// Round 11
// 159.220 us; speedup vs baseline: 1.2984x; 1.2984x over previous
//
#include <hip/hip_runtime.h>
#include <math.h>

// Problem constants (match reference)
constexpr int   B_    = 2048;
constexpr int   L_    = 8192;
constexpr int   G_    = 256;
constexpr float BETA_ = 0.01f;
constexpr int   PMAX  = L_ + G_ * 7;   // groups padded to 8 bf16 -> 9984 max

// softplus(x) = max(x,0) + log(1+exp(-|x|)) = -log_sigmoid(-x) >= 0.
// HW transcendentals; bf16 storage of these terms validated in R10 (absmax 0.0).
__device__ __forceinline__ float softplus(float x) {
    return fmaxf(x, 0.0f) + __logf(1.0f + __expf(-fabsf(x)));
}

// fp32 -> bf16 round-to-nearest-even (sign-preserving, finite inputs)
__device__ __forceinline__ unsigned short bf16_rn(float f) {
    unsigned u = __float_as_uint(f);
    u += 0x7FFFu + ((u >> 16) & 1u);
    return (unsigned short)(u >> 16);
}

// ---------------------------------------------------------------------------
// k0: counting sort -> padded rank space. Group extents rounded to 8 elems
// (one ds_read_b128 of bf16) ; pad slots stay +0.0 (no sign bit, adds 0).
// ---------------------------------------------------------------------------
extern "C" __global__ __launch_bounds__(1024)
void build_rank_kernel(const int* __restrict__ group_ids,
                       int* __restrict__ g_offs,
                       unsigned short* __restrict__ g_rank)
{
    __shared__ int s_hist[G_];
    __shared__ int s_scan[G_];
    __shared__ int s_cur[G_];

    const int t = threadIdx.x;              // 0..1023

    if (t < G_) s_hist[t] = 0;

    int ids[8];
    #pragma unroll
    for (int i = 0; i < 8; ++i) ids[i] = group_ids[i * 1024 + t];

    __syncthreads();

    #pragma unroll
    for (int i = 0; i < 8; ++i) atomicAdd(&s_hist[ids[i]], 1);
    __syncthreads();

    if (t < G_) s_scan[t] = (s_hist[t] + 7) & ~7;   // pad to 8
    __syncthreads();
    for (int off = 1; off < G_; off <<= 1) {
        int v = 0;
        if (t < G_ && t >= off) v = s_scan[t - off];
        __syncthreads();
        if (t < G_) s_scan[t] += v;
        __syncthreads();
    }

    if (t < G_) {
        const int excl = s_scan[t] - ((s_hist[t] + 7) & ~7);  // padded start
        s_cur[t]  = excl;
        g_offs[t] = excl;
    }
    if (t == 0) g_offs[G_] = s_scan[G_ - 1];
    __syncthreads();

    #pragma unroll
    for (int i = 0; i < 8; ++i) {
        const int l = i * 1024 + t;
        g_rank[l] = (unsigned short)atomicAdd(&s_cur[ids[i]], 1);
    }
}

// ---------------------------------------------------------------------------
// Main kernel: 256 threads (4 waves) per row, 2048 blocks.
//  - Sign-bit encoding: stored bf16 s = y ? -softplus(x) : +softplus(x).
//    Phase 2: -grp_log = sum |s|; meta_y = OR of sign bits (1 v_or per word).
//    Kills the fp32 +1024 channel AND the s_any array: LDS 36 KB -> 20 KB.
//  - 8 blocks/CU x 4 waves = 32 waves/CU (100% occupancy target; R6's 57%
//    at 4x512 was the streaming-concurrency limiter; launch_bounds(256,8)
//    caps VGPR at 64 to guarantee it).
//  - b16 scatter (half the bank-word traffic of R6's b32).
// ---------------------------------------------------------------------------
extern "C" __global__ __launch_bounds__(256, 8)
void meta_loss_kernel(const float* __restrict__ logits,
                      const int*   __restrict__ true_y,
                      const int*   __restrict__ g_offs,
                      const unsigned short* __restrict__ g_rank,
                      float*       __restrict__ out)
{
    __shared__ alignas(16) unsigned short s_row[PMAX];   // 19.97 KB
    __shared__ float s_part[4];

    const int t = threadIdx.x;                  // 0..255
    const int b = blockIdx.x;

    const float4*  lg = (const float4*)(logits + (size_t)b * L_);
    const int4*    ty = (const int4*)(true_y + (size_t)b * L_);
    const ushort4* rk = (const ushort4*)g_rank;

    // group extent (L2-hot); thread t owns group t
    const int o0 = g_offs[t];
    const int o1 = g_offs[t + 1];

    // zero-init padded row: 1248 uint4 (pad slots must be +0.0 bf16)
    uint4* s4 = (uint4*)s_row;
    #pragma unroll
    for (int i = 0; i < 5; ++i) {
        const int j = i * 256 + t;
        if (j < PMAX / 8) s4[j] = make_uint4(0u, 0u, 0u, 0u);
    }
    __syncthreads();

    // ---- Phase 1: stream row -> sign-encoded bf16 scatter ----
    #pragma unroll
    for (int i = 0; i < L_ / (4 * 256); ++i) {          // 8 iters
        const int idx = i * 256 + t;
        const float4  x = lg[idx];
        const int4    y = ty[idx];
        const ushort4 r = rk[idx];
        s_row[r.x] = bf16_rn(y.x ? -softplus(x.x) : softplus(x.x));
        s_row[r.y] = bf16_rn(y.y ? -softplus(x.y) : softplus(x.y));
        s_row[r.z] = bf16_rn(y.z ? -softplus(x.z) : softplus(x.z));
        s_row[r.w] = bf16_rn(y.w ? -softplus(x.w) : softplus(x.w));
    }
    __syncthreads();

    // ---- Phase 2: contiguous b128 gather; sum |.|, OR sign bits ----
    float    sum = 0.0f;
    unsigned orb = 0u;
    for (int j = o0; j < o1; j += 8) {
        const uint4 wv = *(const uint4*)&s_row[j];
        orb |= wv.x | wv.y | wv.z | wv.w;
        sum += __uint_as_float((wv.x & 0x7FFFu) << 16)
             + __uint_as_float( wv.x & 0x7FFF0000u)
             + __uint_as_float((wv.y & 0x7FFFu) << 16)
             + __uint_as_float( wv.y & 0x7FFF0000u)
             + __uint_as_float((wv.z & 0x7FFFu) << 16)
             + __uint_as_float( wv.z & 0x7FFF0000u)
             + __uint_as_float((wv.w & 0x7FFFu) << 16)
             + __uint_as_float( wv.w & 0x7FFF0000u);
    }
    const float gl = -sum;                               // sum log(1 - sigmoid)

    float term;
    if (orb & 0x80008000u) {                             // any true label
        term = fmaxf(gl, -100.0f);                       // meta_y = 1: log(p)
    } else {
        // gl==0 (empty group) -> log1p(-1) = -inf -> clamped to -100
        term = fmaxf(log1pf(-__expf(gl)), -100.0f);      // meta_y = 0
    }

    // block reduction (4 waves)
    #pragma unroll
    for (int off = 32; off > 0; off >>= 1)
        term += __shfl_down(term, off, 64);
    if ((t & 63) == 0) s_part[t >> 6] = term;
    __syncthreads();

    if (t == 0) {
        const float s = s_part[0] + s_part[1] + s_part[2] + s_part[3];
        atomicAdd(out, s * (-BETA_ / ((float)B_ * (float)G_)));
    }
}

extern "C" void kernel_launch(void* const* d_in, const int* in_sizes, int n_in,
                              void* d_out, int out_size, void* d_ws, size_t ws_size,
                              hipStream_t stream) {
    const float* logits    = (const float*)d_in[0];
    const int*   true_y    = (const int*)d_in[1];
    const int*   group_ids = (const int*)d_in[2];
    float*       out       = (float*)d_out;

    // workspace: [0, 2048) offs (257 ints used), [2048, 2048+16384) rank u16
    int*            g_offs = (int*)d_ws;
    unsigned short* g_rank = (unsigned short*)((char*)d_ws + 2048);

    hipMemsetAsync(out, 0, sizeof(float), stream);

    build_rank_kernel<<<1, 1024, 0, stream>>>(group_ids, g_offs, g_rank);
    meta_loss_kernel<<<B_, 256, 0, stream>>>(logits, true_y, g_offs, g_rank, out);
}